// Round 9
// baseline (64.391 us; speedup 1.0000x reference)
//
#include <hip/hip_runtime.h>
#include <hip/hip_bf16.h>
#include <stdint.h>

#define BB 16
#define NN 1024
#define MM 1024
#define DD 128
#define VERY_NEG (-1e30f)
#define LOG2E 1.44269504f
#define NCH 4              // 64-m chunks per quarter (256 m)

using bf16x8 = __attribute__((ext_vector_type(8))) short;
using f32x4  = __attribute__((ext_vector_type(4))) float;
using f32x16 = __attribute__((ext_vector_type(16))) float;
using i32x4  = __attribute__((ext_vector_type(4))) int;

__device__ inline unsigned short f2bf(float f) {
    union { float f; uint32_t u; } cv; cv.f = f;
    uint32_t u = cv.u;
    return (unsigned short)((u + 0x7FFFu + ((u >> 16) & 1u)) >> 16);
}
__device__ inline float bf2f(unsigned short s) {
    union { uint32_t u; float f; } cv; cv.u = ((uint32_t)s) << 16;
    return cv.f;
}
#define EXP2F(x) __builtin_amdgcn_exp2f(x)

__device__ __forceinline__ int cvtpk(float a, float b) {
    int r;
    asm("v_cvt_pk_bf16_f32 %0, %1, %2" : "=v"(r) : "v"(a), "v"(b));
    return r;
}

typedef __attribute__((address_space(3))) unsigned int lds_u32;
typedef const __attribute__((address_space(1))) unsigned int glb_u32;
__device__ __forceinline__ void gl16(const void* g, void* l) {
    __builtin_amdgcn_global_load_lds((glb_u32*)g, (lds_u32*)l, 16, 0, 0);
}

// ---- fused prep: blocks [0,8192) = row-prep; [8192,8704) = transpose ----
__global__ __launch_bounds__(256) void prep_all(
    const float* __restrict__ q, const float* __restrict__ mem,
    const float* __restrict__ wq, const float* __restrict__ wm,
    const float* __restrict__ wqm, const int* __restrict__ mmask,
    float* __restrict__ a, float* __restrict__ c1s,
    unsigned short* __restrict__ qp, unsigned short* __restrict__ mb,
    unsigned short* __restrict__ mt)
{
    __shared__ unsigned short t[64][72];
    if (blockIdx.x < 8192) {
        int wave = (blockIdx.x * 256 + threadIdx.x) >> 6;
        int lane = threadIdx.x & 63;
        bool is_q = wave < BB * NN;
        int row = is_q ? wave : wave - BB * NN;
        const float* src = (is_q ? q : mem) + (size_t)row * DD;
        const float* wd  = is_q ? wq : wm;
        float2 v  = *(const float2*)(src + lane * 2);
        float2 w2 = *(const float2*)(wd + lane * 2);
        float dot = v.x * w2.x + v.y * w2.y;
        #pragma unroll
        for (int o = 32; o; o >>= 1) dot += __shfl_xor(dot, o);
        if (lane == 0) {
            if (is_q) a[row] = dot;
            else {
                int mm = mmask[row];
                c1s[row] = (dot + (mm ? 0.f : VERY_NEG)) * LOG2E;
            }
        }
        float2 s2 = v;
        if (is_q) {
            float2 wv = *(const float2*)(wqm + lane * 2);
            s2.x *= wv.x * LOG2E; s2.y *= wv.y * LOG2E;
        }
        ushort2 o2; o2.x = f2bf(s2.x); o2.y = f2bf(s2.y);
        *(ushort2*)((is_q ? qp : mb) + (size_t)row * DD + lane * 2) = o2;
    } else {
        int bid = blockIdx.x - 8192;
        int dt = bid & 1, mtile = (bid >> 1) & 15, b = bid >> 5;
        int d0 = dt * 64, m0 = mtile * 64;
        int tid = threadIdx.x;
        int cc = tid & 63, rr = tid >> 6;
        #pragma unroll
        for (int r = 0; r < 64; r += 4) {
            float v = mem[((size_t)b * MM + m0 + r + rr) * DD + d0 + cc];
            t[cc][r + rr] = f2bf(v);
        }
        __syncthreads();
        #pragma unroll
        for (int r = 0; r < 64; r += 4) {
            mt[((size_t)b * DD + d0 + r + rr) * MM + m0 + cc] = t[r + rr][cc];
        }
    }
}

// ---- flash main: grid 512 (16b x 8nt x 4mh), 4 waves/block, wave = 32 q-rows,
//      32x32x16 MFMA, m-quarter of 256 in 64-m chunks (shared staging, dbuf).
//      Softmax q-lane-local (1 shfl_xor(32)); P in-register via cvt_pk + shfl;
//      defer-max rescale (THR=8). Outputs l-normalized bf16 partials + (tmax,l'). ----
__global__ __launch_bounds__(256) void flash_fwd(
    const unsigned short* __restrict__ qp, const unsigned short* __restrict__ mb,
    const unsigned short* __restrict__ mt,
    const float* __restrict__ c1s, const int* __restrict__ qmask,
    unsigned short* __restrict__ Opart, float2* __restrict__ ml)
{
    __shared__ unsigned short stg[2][32 * 512];        // 64 KB: 32 1KB slots per buf
    __shared__ float c1L[256];                         // 1 KB

    int tid = threadIdx.x;
    int w = tid >> 6, lane = tid & 63;
    int l31 = lane & 31, hi = lane >> 5, hi4 = hi * 4;
    bool lo = (lane < 32);
    // XCD swizzle: same-batch blocks land on one XCD's L2 (512 = 8 xcd x 64)
    int wk = (blockIdx.x & 7) * 64 + (blockIdx.x >> 3);
    int b = wk >> 5, mh = (wk >> 3) & 3, nt = wk & 7;
    int n0q = nt * 128 + w * 32;
    int mbase = mh * 256;

    const unsigned short* mbB = mb + (size_t)b * MM * DD;
    const unsigned short* mtB = mt + (size_t)b * DD * MM;

    if (tid < 64) {
        float4 cv = *(const float4*)(c1s + b * MM + mbase + tid * 4);
        *(float4*)&c1L[tid * 4] = cv;
    }

    // Q' B-frags: lane l holds Q'[q = l&31][d = dk*16 + (l>>5)*8 + j]
    const unsigned short* qpb = qp + ((size_t)b * NN + n0q) * DD;
    bf16x8 qf[8];
    #pragma unroll
    for (int dk = 0; dk < 8; dk++)
        qf[dk] = *(const bf16x8*)(qpb + l31 * DD + dk * 16 + hi * 8);

    int qmv = qmask[b * NN + n0q + l31];

    float m_run = -INFINITY, l_run = 0.f, tmax = -INFINITY;
    f32x16 o[4];
    #pragma unroll
    for (int d0 = 0; d0 < 4; d0++)
        #pragma unroll
        for (int r = 0; r < 16; r++) o[d0][r] = 0.f;

    // staging: 32 slots (16 A + 16 V), wave w issues slots w*8..w*8+7
    auto stage = [&](int m0, unsigned short* buf) {
        #pragma unroll
        for (int i = 0; i < 8; i++) {
            int s = w * 8 + i;
            const unsigned short* g;
            if (s < 16) {        // A slot (t = s>>3, dk = s&7): mem[m][d]
                g = mbB + (size_t)(m0 + (s >> 3) * 32 + l31) * DD + (s & 7) * 16 + hi * 8;
            } else {             // V slot (d0 = (s-16)>>2, kh = (s-16)&3): mt[d][m]
                int s2 = s - 16;
                g = mtB + (size_t)((s2 >> 2) * 32 + l31) * MM + m0 + (s2 & 3) * 16 + hi * 8;
            }
            gl16(g, buf + s * 512);
        }
    };

    stage(mbase, stg[0]);
    __syncthreads();   // chunk 0 + c1L resident

    int cur = 0;
    for (int ch = 0; ch < NCH; ch++) {
        int m0 = mbase + ch * 64;
        if (ch + 1 < NCH)
            stage(m0 + 64, stg[cur ^ 1]);   // DMA overlaps compute below

        const unsigned short* bc = stg[cur];

        // QK: two 32q x 32m tiles; A = mem rows from LDS, B = Q' regs
        f32x16 stt[2];
        #pragma unroll
        for (int t = 0; t < 2; t++)
            #pragma unroll
            for (int r = 0; r < 16; r++) stt[t][r] = 0.f;
        #pragma unroll
        for (int t = 0; t < 2; t++)
            #pragma unroll
            for (int dk = 0; dk < 8; dk++) {
                bf16x8 af = *(const bf16x8*)(bc + (t * 8 + dk) * 512 + lane * 8);
                stt[t] = __builtin_amdgcn_mfma_f32_32x32x16_bf16(af, qf[dk], stt[t], 0, 0, 0);
            }

        // bias + mask; S layout: lane holds q=l31, m = m0 + t*32 + (r&3)+8*(r>>2)+4*hi
        float sv[2][16];
        float pmax = -INFINITY;
        #pragma unroll
        for (int t = 0; t < 2; t++)
            #pragma unroll
            for (int rq = 0; rq < 4; rq++) {
                float4 c4 = *(const float4*)&c1L[ch * 64 + t * 32 + rq * 8 + hi4];
                float cc4[4] = {c4.x, c4.y, c4.z, c4.w};
                #pragma unroll
                for (int i = 0; i < 4; i++) {
                    float s = qmv ? (stt[t][rq * 4 + i] + cc4[i]) : 0.f;
                    sv[t][rq * 4 + i] = s;
                    pmax = fmaxf(pmax, s);
                }
            }
        pmax = fmaxf(pmax, __shfl_xor(pmax, 32));
        tmax = fmaxf(tmax, pmax);

        // defer-max: rescale only when chunk max exceeds running max by THR
        if (__any(pmax > m_run + 8.f)) {
            float m_new = fmaxf(m_run, pmax);
            float alphaL = EXP2F(m_run - m_new);
            m_run = m_new;
            l_run *= alphaL;
            #pragma unroll
            for (int rg = 0; rg < 16; rg++) {
                float ar = __shfl(alphaL, ((rg & 3) + 8 * (rg >> 2)) + hi4);
                o[0][rg] *= ar; o[1][rg] *= ar; o[2][rg] *= ar; o[3][rg] *= ar;
            }
        }

        // P = exp2(s - m_run); pack to bf16 in-register; build 4 K=16 A-frags
        float psum = 0.f;
        bf16x8 pfrag[4];
        #pragma unroll
        for (int t = 0; t < 2; t++) {
            float p[16];
            #pragma unroll
            for (int r = 0; r < 16; r++) {
                p[r] = EXP2F(sv[t][r] - m_run);
                psum += p[r];
            }
            #pragma unroll
            for (int h = 0; h < 2; h++) {
                int A0 = cvtpk(p[h * 8 + 0], p[h * 8 + 1]);
                int A1 = cvtpk(p[h * 8 + 2], p[h * 8 + 3]);
                int B0 = cvtpk(p[h * 8 + 4], p[h * 8 + 5]);
                int B1 = cvtpk(p[h * 8 + 6], p[h * 8 + 7]);
                int xA0 = __shfl_xor(A0, 32), xA1 = __shfl_xor(A1, 32);
                int xB0 = __shfl_xor(B0, 32), xB1 = __shfl_xor(B1, 32);
                i32x4 fw;
                fw[0] = lo ? A0 : xB0;
                fw[1] = lo ? A1 : xB1;
                fw[2] = lo ? xA0 : B0;
                fw[3] = lo ? xA1 : B1;
                pfrag[t * 2 + h] = __builtin_bit_cast(bf16x8, fw);
            }
        }
        psum += __shfl_xor(psum, 32);
        l_run += psum;

        // PV: O[q][d] over 4 d-tiles x 4 K=16 steps; V from LDS (linear)
        #pragma unroll
        for (int d0 = 0; d0 < 4; d0++) {
            f32x16 oo = o[d0];
            #pragma unroll
            for (int k4 = 0; k4 < 4; k4++) {
                bf16x8 vf = *(const bf16x8*)(bc + (16 + d0 * 4 + k4) * 512 + lane * 8);
                oo = __builtin_amdgcn_mfma_f32_32x32x16_bf16(pfrag[k4], vf, oo, 0, 0, 0);
            }
            o[d0] = oo;
        }

        __syncthreads();   // drains next-chunk DMA; all waves done with buf[cur]
        cur ^= 1;
    }

    // ---- epilogue: l-normalized bf16 partials + (tmax, l') ----
    float invL = 1.f / l_run;
    size_t rbase = ((size_t)mh * BB + b) * NN + n0q;
    #pragma unroll
    for (int rg = 0; rg < 16; rg++) {
        float ir = __shfl(invL, ((rg & 3) + 8 * (rg >> 2)) + hi4);
        int qv = (rg & 3) + 8 * (rg >> 2) + hi4;
        size_t rowb = (rbase + qv) * DD + l31;
        Opart[rowb + 0 * 32] = f2bf(o[0][rg] * ir);
        Opart[rowb + 1 * 32] = f2bf(o[1][rg] * ir);
        Opart[rowb + 2 * 32] = f2bf(o[2][rg] * ir);
        Opart[rowb + 3 * 32] = f2bf(o[3][rg] * ir);
    }
    if (lo) {
        float2 v; v.x = tmax; v.y = l_run * EXP2F(m_run - tmax);
        ml[rbase + l31] = v;
    }
}

// ---- merge: combine 4 m-quarters per row; writes out1 + rowmax ----
__global__ __launch_bounds__(256) void merge_kernel(
    const unsigned short* __restrict__ Opart, const float2* __restrict__ ml,
    const float* __restrict__ a, const int* __restrict__ qmask,
    float* __restrict__ out1, float* __restrict__ rowmax)
{
    int R = blockIdx.x * 2 + (threadIdx.x >> 7);   // global row in [0, B*N)
    int d = threadIdx.x & 127;
    float2 mlv[4];
    float M = -INFINITY;
    #pragma unroll
    for (int k = 0; k < 4; k++) {
        mlv[k] = ml[(size_t)k * BB * NN + R];
        M = fmaxf(M, mlv[k].x);
    }
    float wgt[4], Z = 0.f;
    #pragma unroll
    for (int k = 0; k < 4; k++) {
        wgt[k] = mlv[k].y * EXP2F(mlv[k].x - M);
        Z += wgt[k];
    }
    float acc = 0.f;
    #pragma unroll
    for (int k = 0; k < 4; k++)
        acc += bf2f(Opart[((size_t)k * BB * NN + R) * DD + d]) * wgt[k];
    out1[(size_t)R * DD + d] = acc / Z;
    if (d == 0)
        rowmax[R] = M * (1.f / LOG2E) + a[R] + (qmask[R] ? 0.f : VERY_NEG);
}

// ---- m2q partials: block = (b, chunk of 64 n-rows), 256 blocks ----
__global__ __launch_bounds__(256) void m2q_partial(
    const float* __restrict__ rowmax, const float* __restrict__ query,
    float* __restrict__ partial, float* __restrict__ Zbuf)
{
    int bid = blockIdx.x;
    int b = bid >> 4, ch = bid & 15;
    int tid = threadIdx.x, lane = tid & 63, wv = tid >> 6;
    __shared__ float red[8];
    __shared__ float pe[64];
    __shared__ float acc1[128];

    float4 rv = *(const float4*)(rowmax + b * NN + tid * 4);
    float mx = fmaxf(fmaxf(rv.x, rv.y), fmaxf(rv.z, rv.w));
    #pragma unroll
    for (int o = 32; o; o >>= 1) mx = fmaxf(mx, __shfl_xor(mx, o));
    if (lane == 0) red[wv] = mx;
    __syncthreads();
    mx = fmaxf(fmaxf(red[0], red[1]), fmaxf(red[2], red[3]));
    float ls = __expf(rv.x - mx) + __expf(rv.y - mx) + __expf(rv.z - mx) + __expf(rv.w - mx);
    #pragma unroll
    for (int o = 32; o; o >>= 1) ls += __shfl_xor(ls, o);
    if (lane == 0) red[4 + wv] = ls;
    if (tid < 64) pe[tid] = __expf(rowmax[b * NN + ch * 64 + tid] - mx);
    __syncthreads();
    float Z = (red[4] + red[5]) + (red[6] + red[7]);

    int d = tid & 127, h = tid >> 7;
    const float* qb = query + ((size_t)b * NN + ch * 64 + h * 32) * DD + d;
    float acc = 0.f;
    #pragma unroll 8
    for (int n = 0; n < 32; n++) acc += pe[h * 32 + n] * qb[(size_t)n * DD];
    if (h) acc1[d] = acc;
    __syncthreads();
    if (!h) partial[(b * 16 + ch) * DD + d] = acc + acc1[d];
    if (tid == 0) Zbuf[b] = Z;
}

// ---- bcast (fused final combine): out2[b][n][d] = (sum_ch partial)/Z ----
__global__ __launch_bounds__(256) void bcast_kernel(
    const float* __restrict__ partial, const float* __restrict__ Zbuf,
    float4* __restrict__ out2)
{
    __shared__ float m2qL[128];
    int i = blockIdx.x * 256 + threadIdx.x;   // 524288 float4s; 128 blocks per b
    int b = i >> 15;
    int tid = threadIdx.x;
    if (tid < 128) {
        float s = 0.f;
        #pragma unroll
        for (int ch = 0; ch < 16; ch++) s += partial[(b * 16 + ch) * DD + tid];
        m2qL[tid] = s / Zbuf[b];
    }
    __syncthreads();
    out2[i] = ((const float4*)m2qL)[i & 31];
}

extern "C" void kernel_launch(void* const* d_in, const int* in_sizes, int n_in,
                              void* d_out, int out_size, void* d_ws, size_t ws_size,
                              hipStream_t stream)
{
    const float* query  = (const float*)d_in[0];
    const float* memory = (const float*)d_in[1];
    const float* w_q    = (const float*)d_in[2];
    const float* w_m    = (const float*)d_in[3];
    const float* w_qm   = (const float*)d_in[4];
    const int*   qmask  = (const int*)d_in[5];
    const int*   mmask  = (const int*)d_in[6];
    float* out1 = (float*)d_out;
    float* out2 = out1 + (size_t)BB * NN * DD;

    char* ws = (char*)d_ws;
    float* a       = (float*)ws;                 // B*N
    float* c1s     = a + BB * NN;                // B*M
    float* rowmax  = c1s + BB * MM;              // B*N
    float* partial = rowmax + BB * NN;           // B*16*D
    float* Zbuf    = partial + BB * 16 * DD;     // B
    unsigned short* qp = (unsigned short*)(ws + (1 << 20));
    unsigned short* mb = qp + (size_t)BB * NN * DD;
    unsigned short* mt = mb + (size_t)BB * MM * DD;
    unsigned short* Opart = (unsigned short*)(ws + (16u << 20));   // 4 * B*N*D bf16
    float2* mlbuf  = (float2*)(ws + (32u << 20));                  // 4 * B*N float2

    prep_all<<<dim3(8192 + 512), 256, 0, stream>>>(query, memory, w_q, w_m, w_qm, mmask,
                                                   a, c1s, qp, mb, mt);
    flash_fwd<<<dim3(512), 256, 0, stream>>>(qp, mb, mt, c1s, qmask, Opart, mlbuf);
    merge_kernel<<<dim3(BB * NN / 2), 256, 0, stream>>>(Opart, mlbuf, a, qmask, out1, rowmax);
    m2q_partial<<<dim3(BB * 16), 256, 0, stream>>>(rowmax, query, partial, Zbuf);
    bcast_kernel<<<dim3(2048), 256, 0, stream>>>(partial, Zbuf, (float4*)out2);
}